// Round 1
// baseline (602.148 us; speedup 1.0000x reference)
//
#include <hip/hip_runtime.h>
#include <hip/hip_bf16.h>

#define NN 131072
#define NE 1048576

typedef unsigned short u16;

__device__ __forceinline__ float bf2f(u16 u) {
  return __uint_as_float(((unsigned int)u) << 16);
}
__device__ __forceinline__ u16 f2bf(float f) {
  unsigned int u = __float_as_uint(f);
  unsigned int r = ((u >> 16) & 1u) + 0x7fffu;
  return (u16)((u + r) >> 16);
}
__device__ __forceinline__ float leakyf(float x) { return x >= 0.f ? x : 0.2f * x; }

// ---------------- workspace layout (bytes) ----------------
// h2 (bf16, N*256)    : [0, 64MB)   -- aliases h1/as1n/ad1n (dead before h2 written)
//   h1 (bf16, N*64)   : [0, 16MB)
//   as1n (f32, N*8)   : [16MB, 20MB)
//   ad1n (f32, N*8)   : [20MB, 24MB)
// h1b (bf16, N*64)    : 64MB..80MB
// as2n/ad2n (f32, N)  : 80MB..81MB
// row_ptr (N+1 int), woff (N int), col (E int), M1, c1, bsum follow.  Total ~90.3MB.
constexpr size_t OFF_H2   = 0;
constexpr size_t OFF_H1   = 0;
constexpr size_t OFF_AS1N = (size_t)NN * 64 * 2;             // 16,777,216
constexpr size_t OFF_AD1N = OFF_AS1N + (size_t)NN * 8 * 4;   // 20,971,520
constexpr size_t OFF_H1B  = (size_t)NN * 256 * 2;            // 67,108,864
constexpr size_t OFF_AS2N = OFF_H1B + (size_t)NN * 64 * 2;   // 83,886,080
constexpr size_t OFF_AD2N = OFF_AS2N + (size_t)NN * 4;
constexpr size_t OFF_RP   = OFF_AD2N + (size_t)NN * 4;
constexpr size_t OFF_WOFF = OFF_RP + (size_t)(NN + 1) * 4;
constexpr size_t OFF_COL  = OFF_WOFF + (size_t)NN * 4;
constexpr size_t OFF_M1   = OFF_COL + (size_t)NE * 4;
constexpr size_t OFF_C1   = OFF_M1 + 64 * 128 * 4;
constexpr size_t OFF_BSUM = OFF_C1 + 256;

// ---------------- CSR build ----------------
__global__ __launch_bounds__(256) void zero_kernel(int* p) {
  p[blockIdx.x * 256 + threadIdx.x] = 0;
}
__global__ __launch_bounds__(256) void count_kernel(const int* ei, int* cnt) {
  int i = blockIdx.x * 256 + threadIdx.x;
  atomicAdd(&cnt[ei[NE + i]], 1);
}
__global__ __launch_bounds__(1024) void scanA_kernel(const int* cnt, int* rp, int* bsum) {
  __shared__ int buf[1024];
  int t = threadIdx.x;
  int i = blockIdx.x * 1024 + t;
  int v = cnt[i];
  buf[t] = v;
  __syncthreads();
  for (int off = 1; off < 1024; off <<= 1) {
    int a = (t >= off) ? buf[t - off] : 0;
    __syncthreads();
    buf[t] += a;
    __syncthreads();
  }
  rp[i] = buf[t] - v;  // block-local exclusive
  if (t == 1023) bsum[blockIdx.x] = buf[t];
}
__global__ void scanB_kernel(int* bsum, int* rp) {
  if (threadIdx.x == 0) {
    int run = 0;
    for (int b = 0; b < 128; ++b) { int v = bsum[b]; bsum[b] = run; run += v; }
    rp[NN] = run;
  }
}
__global__ __launch_bounds__(1024) void scanC_kernel(int* rp, const int* bsum, int* wo) {
  int i = blockIdx.x * 1024 + threadIdx.x;
  int v = rp[i] + bsum[blockIdx.x];
  rp[i] = v;
  wo[i] = v;
}
__global__ __launch_bounds__(256) void fill_kernel(const int* ei, int* wo, int* colv) {
  int i = blockIdx.x * 256 + threadIdx.x;
  int dst = ei[NE + i];
  int pos = atomicAdd(&wo[dst], 1);
  colv[pos] = ei[i];
}

// ---------------- fold BN + We into W1: M1[64][128], c1[64] ----------------
__global__ __launch_bounds__(256) void fold_kernel(const float* W1, const float* We,
                                                   const float* be, const float* gamma,
                                                   const float* beta, const float* mean,
                                                   const float* var, float* M1, float* c1) {
  __shared__ float sg[256];
  __shared__ float ofs[256];
  int t = threadIdx.x;
  float s = gamma[t] * rsqrtf(var[t] + 1e-5f);
  sg[t] = s;
  ofs[t] = (be[t] - mean[t]) * s + beta[t];
  __syncthreads();
  int idx = blockIdx.x * 256 + t;  // 0..8191
  int j = idx >> 7, k = idx & 127;
  float acc = 0.f;
  for (int c = 0; c < 256; ++c) acc += W1[j * 256 + c] * sg[c] * We[c * 128 + k];
  M1[idx] = acc;
  if (blockIdx.x == 0 && t < 64) {
    float a = 0.f;
    for (int c = 0; c < 256; ++c) a += W1[t * 256 + c] * ofs[c];
    c1[t] = a;
  }
}

// ---------------- h1 = x @ M1^T + c1 ; also per-head attention dots ----------------
__global__ __launch_bounds__(256) void gemm_h1_kernel(const float* x, const float* M1,
                                                      const float* c1, const float* as1,
                                                      const float* ad1, u16* h1,
                                                      float* as1n, float* ad1n) {
  __shared__ float sM[64 * 129];  // padded: stride 129 breaks bank conflicts
  __shared__ float sA[16 * 128];
  __shared__ float sc1[64], s_as[64], s_ad[64];
  int t = threadIdx.x;
  for (int i = t; i < 64 * 128; i += 256) sM[(i >> 7) * 129 + (i & 127)] = M1[i];
  if (t < 64) { sc1[t] = c1[t]; s_as[t] = as1[t]; s_ad[t] = ad1[t]; }
  int row0 = blockIdx.x * 16;
  for (int i = t; i < 16 * 128; i += 256) sA[i] = x[(size_t)row0 * 128 + i];
  __syncthreads();
  int col = t & 63;  // lane == output col
  int rq  = t >> 6;  // wave id -> rows rq*4 .. rq*4+3
  float acc[4] = {0.f, 0.f, 0.f, 0.f};
  for (int k = 0; k < 128; ++k) {
    float m = sM[col * 129 + k];
    acc[0] += sA[(rq * 4 + 0) * 128 + k] * m;
    acc[1] += sA[(rq * 4 + 1) * 128 + k] * m;
    acc[2] += sA[(rq * 4 + 2) * 128 + k] * m;
    acc[3] += sA[(rq * 4 + 3) * 128 + k] * m;
  }
  int head = col >> 3;
#pragma unroll
  for (int r = 0; r < 4; ++r) {
    int row = row0 + rq * 4 + r;
    float v = acc[r] + sc1[col];
    h1[(size_t)row * 64 + col] = f2bf(v);
    float ps = v * s_as[col];
    float pd = v * s_ad[col];
    for (int o = 1; o < 8; o <<= 1) { ps += __shfl_xor(ps, o); pd += __shfl_xor(pd, o); }
    if ((col & 7) == 0) { as1n[(size_t)row * 8 + head] = ps; ad1n[(size_t)row * 8 + head] = pd; }
  }
}

// ---------------- GAT1 aggregation: wave per node, lane = head*8 + c ----------------
__global__ __launch_bounds__(256) void gat1_agg_kernel(const int* rp, const int* colv,
                                                       const float* as1n, const float* ad1n,
                                                       const u16* h1, const float* b1,
                                                       u16* h1b) {
  int t = threadIdx.x, lane = t & 63, wv = t >> 6;
  int n = blockIdx.x * 4 + wv;
  int head = lane >> 3;
  int start = rp[n], end = rp[n + 1];
  float ad = ad1n[(size_t)n * 8 + head];
  // self-loop
  float w = __expf(leakyf(as1n[(size_t)n * 8 + head] + ad));
  float denom = w;
  float acc = w * bf2f(h1[(size_t)n * 64 + lane]);
  for (int base = start; base < end; base += 64) {
    int m = end - base; if (m > 64) m = 64;
    int s_l = (lane < m) ? colv[base + lane] : 0;
    for (int i = 0; i < m; ++i) {
      int s = __shfl(s_l, i);
      float wi = __expf(leakyf(as1n[(size_t)s * 8 + head] + ad));
      denom += wi;
      acc += wi * bf2f(h1[(size_t)s * 64 + lane]);
    }
  }
  float v = acc / (denom + 1e-16f) + b1[lane];
  v = v > 0.f ? v : expm1f(v);  // ELU
  h1b[(size_t)n * 64 + lane] = f2bf(v);
}

// ---------------- h2 = h1b @ W2^T (bf16 out, no bias) ----------------
__global__ __launch_bounds__(256) void gemm_h2_kernel(const u16* h1b, const float* W2, u16* h2) {
  __shared__ float sA[32 * 64];  // 32 rows of A, f32
  int t = threadIdx.x, lane = t & 63;
  int row0 = blockIdx.x * 32;
  int r0 = (t >> 6) * 8;  // wave -> 8 rows
  int c0 = lane * 4;      // lane -> 4 cols
  for (int i = t; i < 32 * 64; i += 256) sA[i] = bf2f(h1b[(size_t)row0 * 64 + i]);
  __syncthreads();
  const float4* sA4 = (const float4*)sA;
  float acc[8][4];
#pragma unroll
  for (int r = 0; r < 8; ++r)
#pragma unroll
    for (int j = 0; j < 4; ++j) acc[r][j] = 0.f;
#pragma unroll
  for (int k4 = 0; k4 < 16; ++k4) {
    float4 a[8];
#pragma unroll
    for (int r = 0; r < 8; ++r) a[r] = sA4[(r0 + r) * 16 + k4];
#pragma unroll
    for (int j = 0; j < 4; ++j) {
      float4 w = ((const float4*)(W2 + (size_t)(c0 + j) * 64))[k4];
#pragma unroll
      for (int r = 0; r < 8; ++r) {
        acc[r][j] += a[r].x * w.x;
        acc[r][j] += a[r].y * w.y;
        acc[r][j] += a[r].z * w.z;
        acc[r][j] += a[r].w * w.w;
      }
    }
  }
#pragma unroll
  for (int r = 0; r < 8; ++r) {
    ushort4 o;
    o.x = f2bf(acc[r][0]); o.y = f2bf(acc[r][1]); o.z = f2bf(acc[r][2]); o.w = f2bf(acc[r][3]);
    ((ushort4*)(h2 + (size_t)(row0 + r0 + r) * 256))[lane] = o;
  }
}

// ---------------- attention dots for GAT2 ----------------
__global__ __launch_bounds__(256) void attdot2_kernel(const u16* h2, const float* as2,
                                                      const float* ad2, float* as2n, float* ad2n) {
  int t = threadIdx.x, lane = t & 63, wv = t >> 6;
  int n = blockIdx.x * 4 + wv;
  ushort4 v = ((const ushort4*)(h2 + (size_t)n * 256))[lane];
  float4 a = ((const float4*)as2)[lane];
  float4 d = ((const float4*)ad2)[lane];
  float x0 = bf2f(v.x), x1 = bf2f(v.y), x2 = bf2f(v.z), x3 = bf2f(v.w);
  float ps = x0 * a.x + x1 * a.y + x2 * a.z + x3 * a.w;
  float pd = x0 * d.x + x1 * d.y + x2 * d.z + x3 * d.w;
  for (int o = 1; o < 64; o <<= 1) { ps += __shfl_xor(ps, o); pd += __shfl_xor(pd, o); }
  if (lane == 0) { as2n[n] = ps; ad2n[n] = pd; }
}

// ------- GAT2 aggregation + bias + fused mu = out2.Wo + bo; writes zeros half -------
__global__ __launch_bounds__(256) void gat2_agg_kernel(const int* rp, const int* colv,
                                                       const float* as2n, const float* ad2n,
                                                       const u16* h2, const float* b2,
                                                       const float* Wo, const float* bo,
                                                       float* out) {
  int t = threadIdx.x, lane = t & 63, wv = t >> 6;
  int n = blockIdx.x * 4 + wv;
  int start = rp[n], end = rp[n + 1];
  float ad = ad2n[n];
  float wself = __expf(leakyf(as2n[n] + ad));
  float acc0, acc1, acc2, acc3;
  {
    ushort4 v = ((const ushort4*)(h2 + (size_t)n * 256))[lane];
    acc0 = wself * bf2f(v.x); acc1 = wself * bf2f(v.y);
    acc2 = wself * bf2f(v.z); acc3 = wself * bf2f(v.w);
  }
  float denomp = 0.f;  // per-lane partial over edges
  for (int base = start; base < end; base += 64) {
    int m = end - base; if (m > 64) m = 64;
    int s_l = 0; float w_l = 0.f;
    if (lane < m) {
      s_l = colv[base + lane];
      w_l = __expf(leakyf(as2n[s_l] + ad));
    }
    denomp += w_l;
    for (int i = 0; i < m; ++i) {
      int s = __shfl(s_l, i);
      float w = __shfl(w_l, i);
      ushort4 v = ((const ushort4*)(h2 + (size_t)s * 256))[lane];
      acc0 += w * bf2f(v.x); acc1 += w * bf2f(v.y);
      acc2 += w * bf2f(v.z); acc3 += w * bf2f(v.w);
    }
  }
  for (int o = 1; o < 64; o <<= 1) denomp += __shfl_xor(denomp, o);
  float r = 1.f / (denomp + wself + 1e-16f);
  int c = lane * 4;
  float4 bb = ((const float4*)b2)[lane];
  float4 ww = ((const float4*)Wo)[lane];
  float o0 = acc0 * r + bb.x, o1 = acc1 * r + bb.y;
  float o2 = acc2 * r + bb.z, o3 = acc3 * r + bb.w;
  float p = o0 * ww.x + o1 * ww.y + o2 * ww.z + o3 * ww.w;
  for (int o = 1; o < 64; o <<= 1) p += __shfl_xor(p, o);
  if (lane == 0) {
    out[n] = p + bo[0];
    out[NN + n] = 0.f;  // second output: zeros_like(mu)
  }
}

extern "C" void kernel_launch(void* const* d_in, const int* in_sizes, int n_in,
                              void* d_out, int out_size, void* d_ws, size_t ws_size,
                              hipStream_t stream) {
  const float* x   = (const float*)d_in[0];
  const int*   ei  = (const int*)d_in[1];
  const float* We  = (const float*)d_in[2];
  const float* be  = (const float*)d_in[3];
  const float* bng = (const float*)d_in[4];
  const float* bnb = (const float*)d_in[5];
  const float* bnm = (const float*)d_in[6];
  const float* bnv = (const float*)d_in[7];
  const float* W1  = (const float*)d_in[8];
  const float* as1 = (const float*)d_in[9];
  const float* ad1 = (const float*)d_in[10];
  const float* b1  = (const float*)d_in[11];
  const float* W2  = (const float*)d_in[12];
  const float* as2 = (const float*)d_in[13];
  const float* ad2 = (const float*)d_in[14];
  const float* b2  = (const float*)d_in[15];
  const float* Wo  = (const float*)d_in[16];
  const float* bo  = (const float*)d_in[17];
  float* out = (float*)d_out;

  char* ws = (char*)d_ws;
  u16*   h1   = (u16*)(ws + OFF_H1);
  float* as1n = (float*)(ws + OFF_AS1N);
  float* ad1n = (float*)(ws + OFF_AD1N);
  u16*   h2   = (u16*)(ws + OFF_H2);
  u16*   h1b  = (u16*)(ws + OFF_H1B);
  float* as2n = (float*)(ws + OFF_AS2N);
  float* ad2n = (float*)(ws + OFF_AD2N);
  int*   rp   = (int*)(ws + OFF_RP);
  int*   wo   = (int*)(ws + OFF_WOFF);
  int*   colv = (int*)(ws + OFF_COL);
  float* M1   = (float*)(ws + OFF_M1);
  float* c1   = (float*)(ws + OFF_C1);
  int*   bsum = (int*)(ws + OFF_BSUM);

  // CSR build (by dst)
  zero_kernel<<<NN / 256, 256, 0, stream>>>(wo);
  count_kernel<<<NE / 256, 256, 0, stream>>>(ei, wo);
  scanA_kernel<<<NN / 1024, 1024, 0, stream>>>(wo, rp, bsum);
  scanB_kernel<<<1, 64, 0, stream>>>(bsum, rp);
  scanC_kernel<<<NN / 1024, 1024, 0, stream>>>(rp, bsum, wo);
  fill_kernel<<<NE / 256, 256, 0, stream>>>(ei, wo, colv);

  // folded embed+BN+W1
  fold_kernel<<<32, 256, 0, stream>>>(W1, We, be, bng, bnb, bnm, bnv, M1, c1);
  gemm_h1_kernel<<<NN / 16, 256, 0, stream>>>(x, M1, c1, as1, ad1, h1, as1n, ad1n);
  gat1_agg_kernel<<<NN / 4, 256, 0, stream>>>(rp, colv, as1n, ad1n, h1, b1, h1b);
  gemm_h2_kernel<<<NN / 32, 256, 0, stream>>>(h1b, W2, h2);
  attdot2_kernel<<<NN / 4, 256, 0, stream>>>(h2, as2, ad2, as2n, ad2n);
  gat2_agg_kernel<<<NN / 4, 256, 0, stream>>>(rp, colv, as2n, ad2n, h2, b2, Wo, bo, out);
}

// Round 2
// 337.841 us; speedup vs baseline: 1.7823x; 1.7823x over previous
//
#include <hip/hip_runtime.h>
#include <hip/hip_bf16.h>

#define NN 131072
#define NE 1048576

typedef unsigned short u16;

__device__ __forceinline__ float bf2f(u16 u) {
  return __uint_as_float(((unsigned int)u) << 16);
}
__device__ __forceinline__ u16 f2bf(float f) {
  unsigned int u = __float_as_uint(f);
  unsigned int r = ((u >> 16) & 1u) + 0x7fffu;
  return (u16)((u + r) >> 16);
}
__device__ __forceinline__ float leakyf(float x) { return x >= 0.f ? x : 0.2f * x; }

// ---------------- workspace layout (bytes) ----------------
constexpr size_t OFF_H1   = 0;                                 // bf16 N*64  (16.8MB)
constexpr size_t OFF_AS1N = (size_t)NN * 64 * 2;               // f32 N*8
constexpr size_t OFF_AD1N = OFF_AS1N + (size_t)NN * 8 * 4;     // f32 N*8
constexpr size_t OFF_ZS   = OFF_AD1N + (size_t)NN * 8 * 4;     // float2 N {as2n, z}
constexpr size_t OFF_AD2N = OFF_ZS + (size_t)NN * 8;           // f32 N
constexpr size_t OFF_RP   = OFF_AD2N + (size_t)NN * 4;         // int N+1
constexpr size_t OFF_WOFF = OFF_RP + (size_t)(NN + 1) * 4;     // int N
constexpr size_t OFF_COL  = OFF_WOFF + (size_t)NN * 4;         // int E
constexpr size_t OFF_M1   = OFF_COL + (size_t)NE * 4;          // f32 64*128
constexpr size_t OFF_C1   = OFF_M1 + 64 * 128 * 4;             // f32 64
constexpr size_t OFF_V2   = OFF_C1 + 256;                      // f32 va[64],vd[64],vz[64],cconst
constexpr size_t OFF_BSUM = OFF_V2 + 193 * 4;                  // int 128

// ---------------- CSR build ----------------
__global__ __launch_bounds__(256) void zero_kernel(int* p) {
  p[blockIdx.x * 256 + threadIdx.x] = 0;
}
__global__ __launch_bounds__(256) void count_kernel(const int* ei, int* cnt) {
  int i = blockIdx.x * 256 + threadIdx.x;
  atomicAdd(&cnt[ei[NE + i]], 1);
}
__global__ __launch_bounds__(1024) void scanA_kernel(const int* cnt, int* rp, int* bsum) {
  __shared__ int buf[1024];
  int t = threadIdx.x;
  int i = blockIdx.x * 1024 + t;
  int v = cnt[i];
  buf[t] = v;
  __syncthreads();
  for (int off = 1; off < 1024; off <<= 1) {
    int a = (t >= off) ? buf[t - off] : 0;
    __syncthreads();
    buf[t] += a;
    __syncthreads();
  }
  rp[i] = buf[t] - v;  // block-local exclusive
  if (t == 1023) bsum[blockIdx.x] = buf[t];
}
__global__ void scanB_kernel(int* bsum, int* rp) {
  if (threadIdx.x == 0) {
    int run = 0;
    for (int b = 0; b < 128; ++b) { int v = bsum[b]; bsum[b] = run; run += v; }
    rp[NN] = run;
  }
}
__global__ __launch_bounds__(1024) void scanC_kernel(int* rp, const int* bsum, int* wo) {
  int i = blockIdx.x * 1024 + threadIdx.x;
  int v = rp[i] + bsum[blockIdx.x];
  rp[i] = v;
  wo[i] = v;
}
__global__ __launch_bounds__(256) void fill_kernel(const int* ei, int* wo, int* colv) {
  int i = blockIdx.x * 256 + threadIdx.x;
  int dst = ei[NE + i];
  int pos = atomicAdd(&wo[dst], 1);
  colv[pos] = ei[i];
}

// ---------------- fold BN + We into W1: M1[64][128], c1[64] ----------------
__global__ __launch_bounds__(256) void fold_kernel(const float* W1, const float* We,
                                                   const float* be, const float* gamma,
                                                   const float* beta, const float* mean,
                                                   const float* var, float* M1, float* c1) {
  __shared__ float sg[256];
  __shared__ float ofs[256];
  int t = threadIdx.x;
  float s = gamma[t] * rsqrtf(var[t] + 1e-5f);
  sg[t] = s;
  ofs[t] = (be[t] - mean[t]) * s + beta[t];
  __syncthreads();
  int idx = blockIdx.x * 256 + t;  // 0..8191
  int j = idx >> 7, k = idx & 127;
  float acc = 0.f;
  for (int c = 0; c < 256; ++c) acc += W1[j * 256 + c] * sg[c] * We[c * 128 + k];
  M1[idx] = acc;
  if (blockIdx.x == 0 && t < 64) {
    float a = 0.f;
    for (int c = 0; c < 256; ++c) a += W1[t * 256 + c] * ofs[c];
    c1[t] = a;
  }
}

// ------- fold GAT2: va = W2^T as2, vd = W2^T ad2, vz = W2^T Wo, cconst = b2.Wo + bo -------
__global__ __launch_bounds__(64) void fold2_kernel(const float* W2, const float* as2,
                                                   const float* ad2, const float* Wo,
                                                   const float* b2, const float* bo,
                                                   float* v2) {
  int k = threadIdx.x;  // 0..63
  float a = 0.f, d = 0.f, z = 0.f;
  for (int c = 0; c < 256; ++c) {
    float w = W2[c * 64 + k];
    a += as2[c] * w;
    d += ad2[c] * w;
    z += Wo[c] * w;
  }
  v2[k] = a;
  v2[64 + k] = d;
  v2[128 + k] = z;
  if (k == 0) {
    float cc = 0.f;
    for (int c = 0; c < 256; ++c) cc += b2[c] * Wo[c];
    v2[192] = cc + bo[0];
  }
}

// ---------------- h1 = x @ M1^T + c1 ; also per-head attention dots ----------------
__global__ __launch_bounds__(256) void gemm_h1_kernel(const float* x, const float* M1,
                                                      const float* c1, const float* as1,
                                                      const float* ad1, u16* h1,
                                                      float* as1n, float* ad1n) {
  __shared__ float sM[64 * 129];  // padded: stride 129 breaks bank conflicts
  __shared__ float sA[16 * 128];
  __shared__ float sc1[64], s_as[64], s_ad[64];
  int t = threadIdx.x;
  for (int i = t; i < 64 * 128; i += 256) sM[(i >> 7) * 129 + (i & 127)] = M1[i];
  if (t < 64) { sc1[t] = c1[t]; s_as[t] = as1[t]; s_ad[t] = ad1[t]; }
  int row0 = blockIdx.x * 16;
  for (int i = t; i < 16 * 128; i += 256) sA[i] = x[(size_t)row0 * 128 + i];
  __syncthreads();
  int col = t & 63;  // lane == output col
  int rq  = t >> 6;  // wave id -> rows rq*4 .. rq*4+3
  float acc[4] = {0.f, 0.f, 0.f, 0.f};
  for (int k = 0; k < 128; ++k) {
    float m = sM[col * 129 + k];
    acc[0] += sA[(rq * 4 + 0) * 128 + k] * m;
    acc[1] += sA[(rq * 4 + 1) * 128 + k] * m;
    acc[2] += sA[(rq * 4 + 2) * 128 + k] * m;
    acc[3] += sA[(rq * 4 + 3) * 128 + k] * m;
  }
  int head = col >> 3;
#pragma unroll
  for (int r = 0; r < 4; ++r) {
    int row = row0 + rq * 4 + r;
    float v = acc[r] + sc1[col];
    h1[(size_t)row * 64 + col] = f2bf(v);
    float ps = v * s_as[col];
    float pd = v * s_ad[col];
    for (int o = 1; o < 8; o <<= 1) { ps += __shfl_xor(ps, o); pd += __shfl_xor(pd, o); }
    if ((col & 7) == 0) { as1n[(size_t)row * 8 + head] = ps; ad1n[(size_t)row * 8 + head] = pd; }
  }
}

// ------ GAT1 aggregation + ELU + fused GAT2 node scalars (as2n, ad2n, z) ------
// wave per node, lane = head*8 + c. h1b never stored: the three 64-dim dots
// with va/vd/vz are computed from the in-register result.
__global__ __launch_bounds__(256) void gat1_agg_kernel(const int* rp, const int* colv,
                                                       const float* as1n, const float* ad1n,
                                                       const u16* h1, const float* b1,
                                                       const float* v2, float2* zs,
                                                       float* ad2n) {
  int t = threadIdx.x, lane = t & 63, wv = t >> 6;
  int n = blockIdx.x * 4 + wv;
  int head = lane >> 3;
  int start = rp[n], end = rp[n + 1];
  float ad = ad1n[(size_t)n * 8 + head];
  // self-loop
  float w = __expf(leakyf(as1n[(size_t)n * 8 + head] + ad));
  float denom = w;
  float acc = w * bf2f(h1[(size_t)n * 64 + lane]);
  for (int base = start; base < end; base += 64) {
    int m = end - base; if (m > 64) m = 64;
    int s_l = (lane < m) ? colv[base + lane] : 0;
    for (int i = 0; i < m; ++i) {
      int s = __shfl(s_l, i);
      float wi = __expf(leakyf(as1n[(size_t)s * 8 + head] + ad));
      denom += wi;
      acc += wi * bf2f(h1[(size_t)s * 64 + lane]);
    }
  }
  float v = acc / (denom + 1e-16f) + b1[lane];
  v = v > 0.f ? v : expm1f(v);  // ELU
  // fused: three 64-dim dots -> GAT2 node scalars
  float p0 = v * v2[lane];        // as2n
  float p1 = v * v2[64 + lane];   // ad2n
  float p2 = v * v2[128 + lane];  // z
  for (int o = 1; o < 64; o <<= 1) {
    p0 += __shfl_xor(p0, o);
    p1 += __shfl_xor(p1, o);
    p2 += __shfl_xor(p2, o);
  }
  if (lane == 0) {
    zs[n] = make_float2(p0, p2);
    ad2n[n] = p1;
  }
}

// ------- GAT2 collapsed to scalar aggregation: thread per node -------
__global__ __launch_bounds__(256) void gat2_kernel(const int* rp, const int* colv,
                                                   const float2* zs, const float* ad2n,
                                                   const float* v2, float* out) {
  int n = blockIdx.x * 256 + threadIdx.x;
  int start = rp[n], end = rp[n + 1];
  float ad = ad2n[n];
  float2 self = zs[n];
  float w = __expf(leakyf(self.x + ad));
  float num = w * self.y;
  float den = w;
  for (int e = start; e < end; ++e) {
    int s = colv[e];
    float2 t = zs[s];
    float wi = __expf(leakyf(t.x + ad));
    num += wi * t.y;
    den += wi;
  }
  out[n] = num / (den + 1e-16f) + v2[192];
  out[NN + n] = 0.f;  // second output: zeros_like(mu)
}

extern "C" void kernel_launch(void* const* d_in, const int* in_sizes, int n_in,
                              void* d_out, int out_size, void* d_ws, size_t ws_size,
                              hipStream_t stream) {
  const float* x   = (const float*)d_in[0];
  const int*   ei  = (const int*)d_in[1];
  const float* We  = (const float*)d_in[2];
  const float* be  = (const float*)d_in[3];
  const float* bng = (const float*)d_in[4];
  const float* bnb = (const float*)d_in[5];
  const float* bnm = (const float*)d_in[6];
  const float* bnv = (const float*)d_in[7];
  const float* W1  = (const float*)d_in[8];
  const float* as1 = (const float*)d_in[9];
  const float* ad1 = (const float*)d_in[10];
  const float* b1  = (const float*)d_in[11];
  const float* W2  = (const float*)d_in[12];
  const float* as2 = (const float*)d_in[13];
  const float* ad2 = (const float*)d_in[14];
  const float* b2  = (const float*)d_in[15];
  const float* Wo  = (const float*)d_in[16];
  const float* bo  = (const float*)d_in[17];
  float* out = (float*)d_out;

  char* ws = (char*)d_ws;
  u16*    h1   = (u16*)(ws + OFF_H1);
  float*  as1n = (float*)(ws + OFF_AS1N);
  float*  ad1n = (float*)(ws + OFF_AD1N);
  float2* zs   = (float2*)(ws + OFF_ZS);
  float*  ad2n = (float*)(ws + OFF_AD2N);
  int*    rp   = (int*)(ws + OFF_RP);
  int*    wo   = (int*)(ws + OFF_WOFF);
  int*    colv = (int*)(ws + OFF_COL);
  float*  M1   = (float*)(ws + OFF_M1);
  float*  c1   = (float*)(ws + OFF_C1);
  float*  v2   = (float*)(ws + OFF_V2);
  int*    bsum = (int*)(ws + OFF_BSUM);

  // CSR build (by dst)
  zero_kernel<<<NN / 256, 256, 0, stream>>>(wo);
  count_kernel<<<NE / 256, 256, 0, stream>>>(ei, wo);
  scanA_kernel<<<NN / 1024, 1024, 0, stream>>>(wo, rp, bsum);
  scanB_kernel<<<1, 64, 0, stream>>>(bsum, rp);
  scanC_kernel<<<NN / 1024, 1024, 0, stream>>>(rp, bsum, wo);
  fill_kernel<<<NE / 256, 256, 0, stream>>>(ei, wo, colv);

  // folded weights
  fold_kernel<<<32, 256, 0, stream>>>(W1, We, be, bng, bnb, bnm, bnv, M1, c1);
  fold2_kernel<<<1, 64, 0, stream>>>(W2, as2, ad2, Wo, b2, bo, v2);

  gemm_h1_kernel<<<NN / 16, 256, 0, stream>>>(x, M1, c1, as1, ad1, h1, as1n, ad1n);
  gat1_agg_kernel<<<NN / 4, 256, 0, stream>>>(rp, colv, as1n, ad1n, h1, b1, v2, zs, ad2n);
  gat2_kernel<<<NN / 256, 256, 0, stream>>>(rp, colv, zs, ad2n, v2, out);
}